// Round 14
// baseline (194.996 us; speedup 1.0000x reference)
//
#include <hip/hip_runtime.h>

#define N_ITER 100
#define CONV_EPS 2e-4f

typedef float f32x4 __attribute__((ext_vector_type(4)));
typedef unsigned u32x4 __attribute__((ext_vector_type(4)));

// RNE-pack two f32 into a dword of two bf16 (proven R7-R13: absmax 3.9e-3).
__device__ __forceinline__ unsigned bf16pack(float a, float b) {
  unsigned ua = __float_as_uint(a), ub = __float_as_uint(b);
  ua = (ua + 0x7FFFu + ((ua >> 16) & 1u)) >> 16;
  ub = (ub + 0x7FFFu + ((ub >> 16) & 1u)) >> 16;
  return ua | (ub << 16);
}
__device__ __forceinline__ float bflo(unsigned u) { return __uint_as_float(u << 16); }
__device__ __forceinline__ float bfhi(unsigned u) { return __uint_as_float(u & 0xFFFF0000u); }

// Force a value's virtual register into AGPR class AT DEFINITION (proven R13:
// kills the accvgpr copy tax without the R11/R12 asm-boundary hazards).
__device__ __forceinline__ void pin_agpr(u32x4& x) {
  asm("" : "=a"(x) : "0"(x));
}

// MFMA with A + accumulator pinned to AGPRs, B in VGPRs (R13-proven hazard
// handling: s_nop 2 entry guard, inline-0 SrcC chain start, 24-cyc data-tied
// exit fence before any VALU reads the MFMA destination).
__device__ __forceinline__ void mfma_first(f32x4& acc, const u32x4& a, const u32x4& b) {
  asm("s_nop 2\n\tv_mfma_f32_16x16x32_bf16 %0, %1, %2, 0"
      : "=&a"(acc) : "a"(a), "v"(b));
}
__device__ __forceinline__ void mfma_aa(f32x4& acc, const u32x4& a, const u32x4& b) {
  asm("s_nop 2\n\tv_mfma_f32_16x16x32_bf16 %0, %1, %2, %0"
      : "+a"(acc) : "a"(a), "v"(b));
}
__device__ __forceinline__ void mfma_fence(f32x4& acc0, f32x4& acc1) {
  asm volatile("s_nop 7\n\ts_nop 7\n\ts_nop 7" : "+a"(acc0), "+a"(acc1));
}

// One block (512 threads = 8 waves) per matrix (R13 structure, proven).
// Wave w owns rows [32w,32w+32) and cols [32w,32w+32) of V0 (bf16 A-frags
// pinned in AGPRs). Scales broadcast through the MFMA B operand.
// NEW (R14): early exit. With bf16-quantized scales the iteration
// bit-stabilizes exactly; row-sum deviation |s_r * R_old_r - 1| then drops to
// rcp-error (~1e-6), so a 2e-4 test must fire. After the break, ONE final
// refinement iteration recomputes scales and writes the f32 copies used by
// the epilogue (hoisted R13 `last` path).
__global__ __launch_bounds__(512)
__attribute__((amdgpu_waves_per_eu(2, 2)))
void sinkhorn_mfma8d(const float* __restrict__ alpha, float* __restrict__ out) {
  __shared__ alignas(16) unsigned short Cb16[256];
  __shared__ alignas(16) unsigned short Rb16[256];
  __shared__ alignas(16) float Cb32[256];
  __shared__ alignas(16) float Rb32[256];
  __shared__ int nc[2];  // ping-pong "not converged" flags (R6-proven pattern)

  const int tid  = threadIdx.x;
  const int lane = tid & 63;
  const int w    = tid >> 6;   // wave 0..7
  const int m    = lane & 15;
  const int q    = lane >> 4;

  const size_t mbase = (size_t)blockIdx.x * (256 * 256);
  const float* A = alpha + mbase;
  float*       O = out + mbase;

  // arow[s][c] elem j <-> V0[32w+16s+m][32c+8q+j]
  // acol[s][c] elem j <-> V0[32c+8q+j][32w+16s+m]
  u32x4 arow[2][8];
  u32x4 acol[2][8];

#pragma unroll
  for (int s = 0; s < 2; ++s) {
    const float* rowp = A + (size_t)(32 * w + 16 * s + m) * 256 + 8 * q;
#pragma unroll
    for (int c = 0; c < 8; ++c) {
      float4 x0 = *(const float4*)(rowp + 32 * c);
      float4 x1 = *(const float4*)(rowp + 32 * c + 4);
      arow[s][c] = (u32x4){bf16pack(__expf(x0.x * 10.0f), __expf(x0.y * 10.0f)),
                           bf16pack(__expf(x0.z * 10.0f), __expf(x0.w * 10.0f)),
                           bf16pack(__expf(x1.x * 10.0f), __expf(x1.y * 10.0f)),
                           bf16pack(__expf(x1.z * 10.0f), __expf(x1.w * 10.0f))};
    }
    const float* colp = A + (size_t)(8 * q) * 256 + 32 * w + 16 * s + m;
#pragma unroll
    for (int c = 0; c < 8; ++c) {
      const float* p = colp + (size_t)(32 * c) * 256;
      acol[s][c] =
          (u32x4){bf16pack(__expf(p[0] * 10.0f), __expf(p[256] * 10.0f)),
                  bf16pack(__expf(p[512] * 10.0f), __expf(p[768] * 10.0f)),
                  bf16pack(__expf(p[1024] * 10.0f), __expf(p[1280] * 10.0f)),
                  bf16pack(__expf(p[1536] * 10.0f), __expf(p[1792] * 10.0f))};
    }
  }
  // Pin all persistent fragments into AGPRs (one-time, far from MFMAs).
#pragma unroll
  for (int s = 0; s < 2; ++s)
#pragma unroll
    for (int c = 0; c < 8; ++c) {
      pin_agpr(arow[s][c]);
      pin_agpr(acol[s][c]);
    }

  if (tid < 256) Cb16[tid] = 0x3F80;  // C = 1
  if (tid == 0) { nc[0] = 0; nc[1] = 0; }
  __syncthreads();

  // Previous-iteration row scales for this lane's 8 rows (valid in m==0 lanes).
  float rp0 = 1.0f, rp1 = 1.0f, rp2 = 1.0f, rp3 = 1.0f;
  float rp4 = 1.0f, rp5 = 1.0f, rp6 = 1.0f, rp7 = 1.0f;

  int it = 0;
  for (; it < N_ITER - 1; ++it) {
    // ---------- phase 1: s = V0_rowslabs · C ; R = 1/s ; conv check ----------
    {
      u32x4 B[8];
#pragma unroll
      for (int c = 0; c < 8; ++c) B[c] = *(const u32x4*)&Cb16[32 * c + 8 * q];
      f32x4 acc0, acc1;
      mfma_first(acc0, arow[0][0], B[0]);
      mfma_first(acc1, arow[1][0], B[0]);
#pragma unroll
      for (int c = 1; c < 8; ++c) {
        mfma_aa(acc0, arow[0][c], B[c]);
        mfma_aa(acc1, arow[1][c], B[c]);
      }
      mfma_fence(acc0, acc1);
      if (tid == 0) nc[(it + 1) & 1] = 0;  // pre-clear next iter's flag
      if (m == 0) {
        // deviation of current matrix's row sums from 1: s_new * R_old
        float d0 = fmaxf(fabsf(fmaf(acc0[0], rp0, -1.0f)), fabsf(fmaf(acc0[1], rp1, -1.0f)));
        float d1 = fmaxf(fabsf(fmaf(acc0[2], rp2, -1.0f)), fabsf(fmaf(acc0[3], rp3, -1.0f)));
        float d2 = fmaxf(fabsf(fmaf(acc1[0], rp4, -1.0f)), fabsf(fmaf(acc1[1], rp5, -1.0f)));
        float d3 = fmaxf(fabsf(fmaf(acc1[2], rp6, -1.0f)), fabsf(fmaf(acc1[3], rp7, -1.0f)));
        float dev = fmaxf(fmaxf(d0, d1), fmaxf(d2, d3));
        if (dev > CONV_EPS) nc[it & 1] = 1;  // racing identical stores: benign
        rp0 = __builtin_amdgcn_rcpf(acc0[0]);
        rp1 = __builtin_amdgcn_rcpf(acc0[1]);
        rp2 = __builtin_amdgcn_rcpf(acc0[2]);
        rp3 = __builtin_amdgcn_rcpf(acc0[3]);
        rp4 = __builtin_amdgcn_rcpf(acc1[0]);
        rp5 = __builtin_amdgcn_rcpf(acc1[1]);
        rp6 = __builtin_amdgcn_rcpf(acc1[2]);
        rp7 = __builtin_amdgcn_rcpf(acc1[3]);
        *(uint2*)&Rb16[32 * w + 4 * q] = make_uint2(bf16pack(rp0, rp1), bf16pack(rp2, rp3));
        *(uint2*)&Rb16[32 * w + 16 + 4 * q] = make_uint2(bf16pack(rp4, rp5), bf16pack(rp6, rp7));
      }
    }
    __syncthreads();  // barrier A

    // ---------- phase 2: t = V0^T_colslabs · R ; C = 1/t ----------
    {
      u32x4 B[8];
#pragma unroll
      for (int c = 0; c < 8; ++c) B[c] = *(const u32x4*)&Rb16[32 * c + 8 * q];
      f32x4 acc0, acc1;
      mfma_first(acc0, acol[0][0], B[0]);
      mfma_first(acc1, acol[1][0], B[0]);
#pragma unroll
      for (int c = 1; c < 8; ++c) {
        mfma_aa(acc0, acol[0][c], B[c]);
        mfma_aa(acc1, acol[1][c], B[c]);
      }
      mfma_fence(acc0, acc1);
      if (m == 0) {
        float c0 = __builtin_amdgcn_rcpf(acc0[0]);
        float c1 = __builtin_amdgcn_rcpf(acc0[1]);
        float c2 = __builtin_amdgcn_rcpf(acc0[2]);
        float c3 = __builtin_amdgcn_rcpf(acc0[3]);
        float c4 = __builtin_amdgcn_rcpf(acc1[0]);
        float c5 = __builtin_amdgcn_rcpf(acc1[1]);
        float c6 = __builtin_amdgcn_rcpf(acc1[2]);
        float c7 = __builtin_amdgcn_rcpf(acc1[3]);
        *(uint2*)&Cb16[32 * w + 4 * q] = make_uint2(bf16pack(c0, c1), bf16pack(c2, c3));
        *(uint2*)&Cb16[32 * w + 16 + 4 * q] = make_uint2(bf16pack(c4, c5), bf16pack(c6, c7));
      }
    }
    __syncthreads();  // barrier B

    if (nc[it & 1] == 0) break;  // all row sums within CONV_EPS -> stabilized
  }

  // ---------- final refinement iteration: f32 scales for the epilogue ----------
  {
    u32x4 B[8];
#pragma unroll
    for (int c = 0; c < 8; ++c) B[c] = *(const u32x4*)&Cb16[32 * c + 8 * q];
    f32x4 acc0, acc1;
    mfma_first(acc0, arow[0][0], B[0]);
    mfma_first(acc1, arow[1][0], B[0]);
#pragma unroll
    for (int c = 1; c < 8; ++c) {
      mfma_aa(acc0, arow[0][c], B[c]);
      mfma_aa(acc1, arow[1][c], B[c]);
    }
    mfma_fence(acc0, acc1);
    if (m == 0) {
      float r0 = __builtin_amdgcn_rcpf(acc0[0]);
      float r1 = __builtin_amdgcn_rcpf(acc0[1]);
      float r2 = __builtin_amdgcn_rcpf(acc0[2]);
      float r3 = __builtin_amdgcn_rcpf(acc0[3]);
      float r4 = __builtin_amdgcn_rcpf(acc1[0]);
      float r5 = __builtin_amdgcn_rcpf(acc1[1]);
      float r6 = __builtin_amdgcn_rcpf(acc1[2]);
      float r7 = __builtin_amdgcn_rcpf(acc1[3]);
      *(uint2*)&Rb16[32 * w + 4 * q] = make_uint2(bf16pack(r0, r1), bf16pack(r2, r3));
      *(uint2*)&Rb16[32 * w + 16 + 4 * q] = make_uint2(bf16pack(r4, r5), bf16pack(r6, r7));
      *(float4*)&Rb32[32 * w + 4 * q] = make_float4(r0, r1, r2, r3);
      *(float4*)&Rb32[32 * w + 16 + 4 * q] = make_float4(r4, r5, r6, r7);
    }
  }
  __syncthreads();
  {
    u32x4 B[8];
#pragma unroll
    for (int c = 0; c < 8; ++c) B[c] = *(const u32x4*)&Rb16[32 * c + 8 * q];
    f32x4 acc0, acc1;
    mfma_first(acc0, acol[0][0], B[0]);
    mfma_first(acc1, acol[1][0], B[0]);
#pragma unroll
    for (int c = 1; c < 8; ++c) {
      mfma_aa(acc0, acol[0][c], B[c]);
      mfma_aa(acc1, acol[1][c], B[c]);
    }
    mfma_fence(acc0, acc1);
    if (m == 0) {
      float c0 = __builtin_amdgcn_rcpf(acc0[0]);
      float c1 = __builtin_amdgcn_rcpf(acc0[1]);
      float c2 = __builtin_amdgcn_rcpf(acc0[2]);
      float c3 = __builtin_amdgcn_rcpf(acc0[3]);
      float c4 = __builtin_amdgcn_rcpf(acc1[0]);
      float c5 = __builtin_amdgcn_rcpf(acc1[1]);
      float c6 = __builtin_amdgcn_rcpf(acc1[2]);
      float c7 = __builtin_amdgcn_rcpf(acc1[3]);
      *(float4*)&Cb32[32 * w + 4 * q] = make_float4(c0, c1, c2, c3);
      *(float4*)&Cb32[32 * w + 16 + 4 * q] = make_float4(c4, c5, c6, c7);
    }
  }
  __syncthreads();

  // ---------- epilogue: out = diag(R32) · V0_bf16 · diag(C32) ----------
#pragma unroll
  for (int s = 0; s < 2; ++s) {
    const float Rm = Rb32[32 * w + 16 * s + m];
    float* dst = O + (size_t)(32 * w + 16 * s + m) * 256 + 8 * q;
#pragma unroll
    for (int c = 0; c < 8; ++c) {
      float4 c0 = *(const float4*)&Cb32[32 * c + 8 * q];
      float4 c1 = *(const float4*)&Cb32[32 * c + 8 * q + 4];
      u32x4 pk = arow[s][c];
      float4 o0, o1;
      o0.x = bflo(pk.x) * Rm * c0.x;
      o0.y = bfhi(pk.x) * Rm * c0.y;
      o0.z = bflo(pk.y) * Rm * c0.z;
      o0.w = bfhi(pk.y) * Rm * c0.w;
      o1.x = bflo(pk.z) * Rm * c1.x;
      o1.y = bfhi(pk.z) * Rm * c1.y;
      o1.z = bflo(pk.w) * Rm * c1.z;
      o1.w = bfhi(pk.w) * Rm * c1.w;
      *(float4*)(dst + 32 * c) = o0;
      *(float4*)(dst + 32 * c + 4) = o1;
    }
  }
}

extern "C" void kernel_launch(void* const* d_in, const int* in_sizes, int n_in,
                              void* d_out, int out_size, void* d_ws, size_t ws_size,
                              hipStream_t stream) {
  const float* alpha = (const float*)d_in[0];
  float* out = (float*)d_out;
  sinkhorn_mfma8d<<<dim3(16), dim3(512), 0, stream>>>(alpha, out);
}

// Round 15
// 191.564 us; speedup vs baseline: 1.0179x; 1.0179x over previous
//
#include <hip/hip_runtime.h>

#define N_ITER 100
#define CONV_EPS 5e-3f

typedef float f32x4 __attribute__((ext_vector_type(4)));
typedef unsigned u32x4 __attribute__((ext_vector_type(4)));

// RNE-pack two f32 into a dword of two bf16 (proven R7-R14: absmax 3.9e-3).
__device__ __forceinline__ unsigned bf16pack(float a, float b) {
  unsigned ua = __float_as_uint(a), ub = __float_as_uint(b);
  ua = (ua + 0x7FFFu + ((ua >> 16) & 1u)) >> 16;
  ub = (ub + 0x7FFFu + ((ub >> 16) & 1u)) >> 16;
  return ua | (ub << 16);
}
__device__ __forceinline__ float bflo(unsigned u) { return __uint_as_float(u << 16); }
__device__ __forceinline__ float bfhi(unsigned u) { return __uint_as_float(u & 0xFFFF0000u); }

// Force a value's virtual register into AGPR class AT DEFINITION (proven R13).
__device__ __forceinline__ void pin_agpr(u32x4& x) {
  asm("" : "=a"(x) : "0"(x));
}

// MFMA with A + accumulator pinned to AGPRs, B in VGPRs (R13-proven hazard
// handling: s_nop 2 entry guard, inline-0 SrcC chain start, 24-cyc data-tied
// exit fence before any VALU reads the MFMA destination).
__device__ __forceinline__ void mfma_first(f32x4& acc, const u32x4& a, const u32x4& b) {
  asm("s_nop 2\n\tv_mfma_f32_16x16x32_bf16 %0, %1, %2, 0"
      : "=&a"(acc) : "a"(a), "v"(b));
}
__device__ __forceinline__ void mfma_aa(f32x4& acc, const u32x4& a, const u32x4& b) {
  asm("s_nop 2\n\tv_mfma_f32_16x16x32_bf16 %0, %1, %2, %0"
      : "+a"(acc) : "a"(a), "v"(b));
}
__device__ __forceinline__ void mfma_fence(f32x4& acc0, f32x4& acc1) {
  asm volatile("s_nop 7\n\ts_nop 7\n\ts_nop 7" : "+a"(acc0), "+a"(acc1));
}

// One block (512 threads = 8 waves) per matrix (R13 structure, proven).
// Early exit (R15): with bf16 scales the iteration enters a +-1-ulp limit
// cycle (amplitude ~2e-3, why R14's 2e-4 never fired); eps=5e-3 sits above
// the cycle amplitude and fires when per-iter change contracts below bf16
// quantization. Checked every 2nd iteration to amortize flag serialization.
__global__ __launch_bounds__(512)
__attribute__((amdgpu_waves_per_eu(2, 2)))
void sinkhorn_mfma8e(const float* __restrict__ alpha, float* __restrict__ out) {
  __shared__ alignas(16) unsigned short Cb16[256];
  __shared__ alignas(16) unsigned short Rb16[256];
  __shared__ alignas(16) float Cb32[256];
  __shared__ alignas(16) float Rb32[256];
  __shared__ int nc[2];  // ping-pong "not converged" flags, slot = (it>>1)&1

  const int tid  = threadIdx.x;
  const int lane = tid & 63;
  const int w    = tid >> 6;   // wave 0..7
  const int m    = lane & 15;
  const int q    = lane >> 4;

  const size_t mbase = (size_t)blockIdx.x * (256 * 256);
  const float* A = alpha + mbase;
  float*       O = out + mbase;

  // arow[s][c] elem j <-> V0[32w+16s+m][32c+8q+j]
  // acol[s][c] elem j <-> V0[32c+8q+j][32w+16s+m]
  u32x4 arow[2][8];
  u32x4 acol[2][8];

#pragma unroll
  for (int s = 0; s < 2; ++s) {
    const float* rowp = A + (size_t)(32 * w + 16 * s + m) * 256 + 8 * q;
#pragma unroll
    for (int c = 0; c < 8; ++c) {
      float4 x0 = *(const float4*)(rowp + 32 * c);
      float4 x1 = *(const float4*)(rowp + 32 * c + 4);
      arow[s][c] = (u32x4){bf16pack(__expf(x0.x * 10.0f), __expf(x0.y * 10.0f)),
                           bf16pack(__expf(x0.z * 10.0f), __expf(x0.w * 10.0f)),
                           bf16pack(__expf(x1.x * 10.0f), __expf(x1.y * 10.0f)),
                           bf16pack(__expf(x1.z * 10.0f), __expf(x1.w * 10.0f))};
    }
    const float* colp = A + (size_t)(8 * q) * 256 + 32 * w + 16 * s + m;
#pragma unroll
    for (int c = 0; c < 8; ++c) {
      const float* p = colp + (size_t)(32 * c) * 256;
      acol[s][c] =
          (u32x4){bf16pack(__expf(p[0] * 10.0f), __expf(p[256] * 10.0f)),
                  bf16pack(__expf(p[512] * 10.0f), __expf(p[768] * 10.0f)),
                  bf16pack(__expf(p[1024] * 10.0f), __expf(p[1280] * 10.0f)),
                  bf16pack(__expf(p[1536] * 10.0f), __expf(p[1792] * 10.0f))};
    }
  }
  // Pin all persistent fragments into AGPRs (one-time, far from MFMAs).
#pragma unroll
  for (int s = 0; s < 2; ++s)
#pragma unroll
    for (int c = 0; c < 8; ++c) {
      pin_agpr(arow[s][c]);
      pin_agpr(acol[s][c]);
    }

  if (tid < 256) Cb16[tid] = 0x3F80;  // C = 1
  if (tid == 0) { nc[0] = 0; nc[1] = 0; }
  __syncthreads();

  // Previous-iteration row scales (valid in m==0 lanes).
  float rp0 = 1.0f, rp1 = 1.0f, rp2 = 1.0f, rp3 = 1.0f;
  float rp4 = 1.0f, rp5 = 1.0f, rp6 = 1.0f, rp7 = 1.0f;

  int it = 0;
  for (; it < N_ITER - 1; ++it) {
    const bool chk = (it & 1) != 0;  // check on odd iterations

    // ---------- phase 1: s = V0_rowslabs · C ; R = 1/s ----------
    {
      u32x4 B[8];
#pragma unroll
      for (int c = 0; c < 8; ++c) B[c] = *(const u32x4*)&Cb16[32 * c + 8 * q];
      f32x4 acc0, acc1;
      mfma_first(acc0, arow[0][0], B[0]);
      mfma_first(acc1, arow[1][0], B[0]);
#pragma unroll
      for (int c = 1; c < 8; ++c) {
        mfma_aa(acc0, arow[0][c], B[c]);
        mfma_aa(acc1, arow[1][c], B[c]);
      }
      mfma_fence(acc0, acc1);
      if (chk) {
        if (tid == 0) nc[((it >> 1) + 1) & 1] = 0;  // pre-clear slot 2 ahead
        if (m == 0) {
          float d0 = fmaxf(fabsf(fmaf(acc0[0], rp0, -1.0f)), fabsf(fmaf(acc0[1], rp1, -1.0f)));
          float d1 = fmaxf(fabsf(fmaf(acc0[2], rp2, -1.0f)), fabsf(fmaf(acc0[3], rp3, -1.0f)));
          float d2 = fmaxf(fabsf(fmaf(acc1[0], rp4, -1.0f)), fabsf(fmaf(acc1[1], rp5, -1.0f)));
          float d3 = fmaxf(fabsf(fmaf(acc1[2], rp6, -1.0f)), fabsf(fmaf(acc1[3], rp7, -1.0f)));
          float dev = fmaxf(fmaxf(d0, d1), fmaxf(d2, d3));
          if (dev > CONV_EPS) nc[(it >> 1) & 1] = 1;  // racing identical stores: benign
        }
      }
      if (m == 0) {
        rp0 = __builtin_amdgcn_rcpf(acc0[0]);
        rp1 = __builtin_amdgcn_rcpf(acc0[1]);
        rp2 = __builtin_amdgcn_rcpf(acc0[2]);
        rp3 = __builtin_amdgcn_rcpf(acc0[3]);
        rp4 = __builtin_amdgcn_rcpf(acc1[0]);
        rp5 = __builtin_amdgcn_rcpf(acc1[1]);
        rp6 = __builtin_amdgcn_rcpf(acc1[2]);
        rp7 = __builtin_amdgcn_rcpf(acc1[3]);
        *(uint2*)&Rb16[32 * w + 4 * q] = make_uint2(bf16pack(rp0, rp1), bf16pack(rp2, rp3));
        *(uint2*)&Rb16[32 * w + 16 + 4 * q] = make_uint2(bf16pack(rp4, rp5), bf16pack(rp6, rp7));
      }
    }
    __syncthreads();  // barrier A

    // ---------- phase 2: t = V0^T_colslabs · R ; C = 1/t ----------
    {
      u32x4 B[8];
#pragma unroll
      for (int c = 0; c < 8; ++c) B[c] = *(const u32x4*)&Rb16[32 * c + 8 * q];
      f32x4 acc0, acc1;
      mfma_first(acc0, acol[0][0], B[0]);
      mfma_first(acc1, acol[1][0], B[0]);
#pragma unroll
      for (int c = 1; c < 8; ++c) {
        mfma_aa(acc0, acol[0][c], B[c]);
        mfma_aa(acc1, acol[1][c], B[c]);
      }
      mfma_fence(acc0, acc1);
      if (m == 0) {
        float c0 = __builtin_amdgcn_rcpf(acc0[0]);
        float c1 = __builtin_amdgcn_rcpf(acc0[1]);
        float c2 = __builtin_amdgcn_rcpf(acc0[2]);
        float c3 = __builtin_amdgcn_rcpf(acc0[3]);
        float c4 = __builtin_amdgcn_rcpf(acc1[0]);
        float c5 = __builtin_amdgcn_rcpf(acc1[1]);
        float c6 = __builtin_amdgcn_rcpf(acc1[2]);
        float c7 = __builtin_amdgcn_rcpf(acc1[3]);
        *(uint2*)&Cb16[32 * w + 4 * q] = make_uint2(bf16pack(c0, c1), bf16pack(c2, c3));
        *(uint2*)&Cb16[32 * w + 16 + 4 * q] = make_uint2(bf16pack(c4, c5), bf16pack(c6, c7));
      }
    }
    __syncthreads();  // barrier B

    if (chk && nc[(it >> 1) & 1] == 0) break;  // stabilized within CONV_EPS
  }

  // ---------- final refinement iteration: f32 scales for the epilogue ----------
  {
    u32x4 B[8];
#pragma unroll
    for (int c = 0; c < 8; ++c) B[c] = *(const u32x4*)&Cb16[32 * c + 8 * q];
    f32x4 acc0, acc1;
    mfma_first(acc0, arow[0][0], B[0]);
    mfma_first(acc1, arow[1][0], B[0]);
#pragma unroll
    for (int c = 1; c < 8; ++c) {
      mfma_aa(acc0, arow[0][c], B[c]);
      mfma_aa(acc1, arow[1][c], B[c]);
    }
    mfma_fence(acc0, acc1);
    if (m == 0) {
      float r0 = __builtin_amdgcn_rcpf(acc0[0]);
      float r1 = __builtin_amdgcn_rcpf(acc0[1]);
      float r2 = __builtin_amdgcn_rcpf(acc0[2]);
      float r3 = __builtin_amdgcn_rcpf(acc0[3]);
      float r4 = __builtin_amdgcn_rcpf(acc1[0]);
      float r5 = __builtin_amdgcn_rcpf(acc1[1]);
      float r6 = __builtin_amdgcn_rcpf(acc1[2]);
      float r7 = __builtin_amdgcn_rcpf(acc1[3]);
      *(uint2*)&Rb16[32 * w + 4 * q] = make_uint2(bf16pack(r0, r1), bf16pack(r2, r3));
      *(uint2*)&Rb16[32 * w + 16 + 4 * q] = make_uint2(bf16pack(r4, r5), bf16pack(r6, r7));
      *(float4*)&Rb32[32 * w + 4 * q] = make_float4(r0, r1, r2, r3);
      *(float4*)&Rb32[32 * w + 16 + 4 * q] = make_float4(r4, r5, r6, r7);
    }
  }
  __syncthreads();
  {
    u32x4 B[8];
#pragma unroll
    for (int c = 0; c < 8; ++c) B[c] = *(const u32x4*)&Rb16[32 * c + 8 * q];
    f32x4 acc0, acc1;
    mfma_first(acc0, acol[0][0], B[0]);
    mfma_first(acc1, acol[1][0], B[0]);
#pragma unroll
    for (int c = 1; c < 8; ++c) {
      mfma_aa(acc0, acol[0][c], B[c]);
      mfma_aa(acc1, acol[1][c], B[c]);
    }
    mfma_fence(acc0, acc1);
    if (m == 0) {
      float c0 = __builtin_amdgcn_rcpf(acc0[0]);
      float c1 = __builtin_amdgcn_rcpf(acc0[1]);
      float c2 = __builtin_amdgcn_rcpf(acc0[2]);
      float c3 = __builtin_amdgcn_rcpf(acc0[3]);
      float c4 = __builtin_amdgcn_rcpf(acc1[0]);
      float c5 = __builtin_amdgcn_rcpf(acc1[1]);
      float c6 = __builtin_amdgcn_rcpf(acc1[2]);
      float c7 = __builtin_amdgcn_rcpf(acc1[3]);
      *(float4*)&Cb32[32 * w + 4 * q] = make_float4(c0, c1, c2, c3);
      *(float4*)&Cb32[32 * w + 16 + 4 * q] = make_float4(c4, c5, c6, c7);
    }
  }
  __syncthreads();

  // ---------- epilogue: out = diag(R32) · V0_bf16 · diag(C32) ----------
#pragma unroll
  for (int s = 0; s < 2; ++s) {
    const float Rm = Rb32[32 * w + 16 * s + m];
    float* dst = O + (size_t)(32 * w + 16 * s + m) * 256 + 8 * q;
#pragma unroll
    for (int c = 0; c < 8; ++c) {
      float4 c0 = *(const float4*)&Cb32[32 * c + 8 * q];
      float4 c1 = *(const float4*)&Cb32[32 * c + 8 * q + 4];
      u32x4 pk = arow[s][c];
      float4 o0, o1;
      o0.x = bflo(pk.x) * Rm * c0.x;
      o0.y = bfhi(pk.x) * Rm * c0.y;
      o0.z = bflo(pk.y) * Rm * c0.z;
      o0.w = bfhi(pk.y) * Rm * c0.w;
      o1.x = bflo(pk.z) * Rm * c1.x;
      o1.y = bfhi(pk.z) * Rm * c1.y;
      o1.z = bflo(pk.w) * Rm * c1.z;
      o1.w = bfhi(pk.w) * Rm * c1.w;
      *(float4*)(dst + 32 * c) = o0;
      *(float4*)(dst + 32 * c + 4) = o1;
    }
  }
}

extern "C" void kernel_launch(void* const* d_in, const int* in_sizes, int n_in,
                              void* d_out, int out_size, void* d_ws, size_t ws_size,
                              hipStream_t stream) {
  const float* alpha = (const float*)d_in[0];
  float* out = (float*)d_out;
  sinkhorn_mfma8e<<<dim3(16), dim3(512), 0, stream>>>(alpha, out);
}